// Round 10
// baseline (355.525 us; speedup 1.0000x reference)
//
#include <hip/hip_runtime.h>
#include <math.h>
#include <stdint.h>

#define CNUM 19
#define NB 4
#define HW 589824            // 768*768
#define NPIX 2359296         // NB*HW

// k_fused: 256 threads = 4 waves per block; TILE = 2048 px per block.
// CHANNEL-SPLIT: wave w owns classes {w, w+4, w+8, ...}. Each wave keeps
// partial sacc/xt for the whole tile in registers (32 px/lane) and per
// channel visit reads 8 KB CONTIGUOUS (8 independent back-to-back 1KB
// loads), software-pipelined one channel ahead. Partials merge via LDS.
#define TPB 256
#define TILE 2048            // px per block; HW % TILE == 0
#define GRP 8                // float4 groups per channel visit (8 x 1KB)

// ---------------------------------------------------------------- workspace
struct ImgAcc2 {
  double sS[CNUM];          // sum of -log p over valid px of class c
  double sA[CNUM];          // same, att-masked (edge > 0.8)
  unsigned int cS[CNUM];    // count (== histogram bin)
  unsigned int cA[CNUM];    // att count (== att histogram bin)
  unsigned int pad[2];
};

struct Ws {
  ImgAcc2 img[NB];
  double bce_p, bce_n;      // sum of bce over pos / neg px (batch-global)
  unsigned int np, nn;      // pos / neg counts (batch-global)
};

// ---------------------------------------------------------------- init
__global__ void k_init(Ws* ws) {
  unsigned int* p = (unsigned int*)ws;
  const int nw = (int)(sizeof(Ws) / 4);
  for (int i = threadIdx.x; i < nw; i += blockDim.x) p[i] = 0u;
}

// ---------------------------------------------------------------- fused main
__global__ __launch_bounds__(TPB) void k_fused(const float* __restrict__ segin,
                                               const float* __restrict__ edgein,
                                               const int* __restrict__ segmask,
                                               const int* __restrict__ edgemask,
                                               Ws* __restrict__ wsw) {
  const int n = blockIdx.y;
  const int t = threadIdx.x;
  const int wv = t >> 6;        // 0..3: channel-group owner
  const int lane = t & 63;
  const int tile0 = blockIdx.x * TILE;

  __shared__ float sacc_l[TILE];                    // 8 KB, summed partials
  __shared__ float xt_l[TILE];                      // 8 KB, owner-written
  __shared__ float lsS[4][CNUM + 1], lsA[4][CNUM + 1];
  __shared__ unsigned int lcS[4][CNUM + 1], lcA[4][CNUM + 1];
  __shared__ float sbp, sbn;
  __shared__ unsigned int snp, snn;

  for (int i = t; i < TILE; i += TPB) sacc_l[i] = 0.f;
  if (t < 4 * (CNUM + 1)) {
    ((float*)lsS)[t] = 0.f; ((float*)lsA)[t] = 0.f;
    ((unsigned int*)lcS)[t] = 0u; ((unsigned int*)lcA)[t] = 0u;
  }
  if (t == 4 * (CNUM + 1)) { sbp = 0.f; sbn = 0.f; snp = 0u; snn = 0u; }
  __syncthreads();

  // ---- per-lane target classes for the 32 px it touches (packed u8x4/grp)
  const int pxbase = n * HW + tile0 + lane * 4;
  unsigned int tcp[GRP];
  #pragma unroll
  for (int g = 0; g < GRP; ++g) {
    int4 tm = *reinterpret_cast<const int4*>(segmask + pxbase + g * 256);
    int a0 = min(max(tm.x, 0), CNUM - 1);
    int a1 = min(max(tm.y, 0), CNUM - 1);
    int a2 = min(max(tm.z, 0), CNUM - 1);
    int a3 = min(max(tm.w, 0), CNUM - 1);
    tcp[g] = (unsigned)a0 | ((unsigned)a1 << 8) | ((unsigned)a2 << 16) | ((unsigned)a3 << 24);
  }

  float sa[GRP][4], xv[GRP][4];
  #pragma unroll
  for (int g = 0; g < GRP; ++g) {
    #pragma unroll
    for (int j = 0; j < 4; ++j) { sa[g][j] = 0.f; xv[g][j] = 0.f; }
  }

  const float* sb = segin + (size_t)n * CNUM * HW + tile0 + lane * 4;

  // ---- channel walk: my channels are wv, wv+4, ..., one-ahead prefetch
  float4 buf[GRP];
  #pragma unroll
  for (int g = 0; g < GRP; ++g)
    buf[g] = *reinterpret_cast<const float4*>(sb + (size_t)wv * HW + g * 256);

  #pragma unroll
  for (int cc = 0; cc < 5; ++cc) {
    const int c = wv + cc * 4;
    if (c < CNUM) {
      float4 cur[GRP];
      #pragma unroll
      for (int g = 0; g < GRP; ++g) cur[g] = buf[g];
      const int cn = c + 4;
      if (cn < CNUM) {
        #pragma unroll
        for (int g = 0; g < GRP; ++g)
          buf[g] = *reinterpret_cast<const float4*>(sb + (size_t)cn * HW + g * 256);
      }
      #pragma unroll
      for (int g = 0; g < GRP; ++g) {
        float va[4] = {cur[g].x, cur[g].y, cur[g].z, cur[g].w};
        #pragma unroll
        for (int j = 0; j < 4; ++j) {
          sa[g][j] += __expf(va[j]);
          int tcj = (int)((tcp[g] >> (8 * j)) & 255u);
          xv[g][j] = (tcj == c) ? va[j] : xv[g][j];
        }
      }
    }
  }

  // ---- merge partials: sacc summed across waves; xt written by owner wave
  #pragma unroll
  for (int g = 0; g < GRP; ++g) {
    const int px = g * 256 + lane * 4;
    #pragma unroll
    for (int j = 0; j < 4; ++j) {
      atomicAdd(&sacc_l[px + j], sa[g][j]);       // ds_add_f32 (no return)
      int tcj = (int)((tcp[g] >> (8 * j)) & 255u);
      if ((tcj & 3) == wv) xt_l[px + j] = xv[g][j];
    }
  }
  __syncthreads();

  // ---- epilogue: thread t owns 8 px of the tile
  const int ep = t * 8;
  const int gpx = n * HW + tile0 + ep;
  int4   sm0 = *reinterpret_cast<const int4*>(segmask + gpx);
  int4   sm1 = *reinterpret_cast<const int4*>(segmask + gpx + 4);
  float4 ev0 = *reinterpret_cast<const float4*>(edgein + gpx);
  float4 ev1 = *reinterpret_cast<const float4*>(edgein + gpx + 4);
  int4   em0 = *reinterpret_cast<const int4*>(edgemask + gpx);
  int4   em1 = *reinterpret_cast<const int4*>(edgemask + gpx + 4);

  int   smv[8] = {sm0.x, sm0.y, sm0.z, sm0.w, sm1.x, sm1.y, sm1.z, sm1.w};
  float eav[8] = {ev0.x, ev0.y, ev0.z, ev0.w, ev1.x, ev1.y, ev1.z, ev1.w};
  int   emv[8] = {em0.x, em0.y, em0.z, em0.w, em1.x, em1.y, em1.z, em1.w};

  float bpos = 0.f, bneg = 0.f;
  int cntp = 0, cntn = 0;
  #pragma unroll
  for (int k = 0; k < 8; ++k) {
    float nlp = __logf(sacc_l[ep + k]) - xt_l[ep + k];   // -log p
    int tgt = smv[k];
    int tcc = min(max(tgt, 0), CNUM - 1);
    bool valid = ((unsigned)tgt) < (unsigned)CNUM;
    if (valid) {
      atomicAdd(&lsS[wv][tcc], nlp);
      atomicAdd(&lcS[wv][tcc], 1u);
      if (eav[k] > 0.8f) {
        atomicAdd(&lsA[wv][tcc], nlp);
        atomicAdd(&lcA[wv][tcc], 1u);
      }
    }
    float e = eav[k];
    int m = emv[k];
    float bce = fmaxf(e, 0.f) - e * (float)m + log1pf(__expf(-fabsf(e)));
    if (m == 1) { bpos += bce; ++cntp; }
    else if (m == 0) { bneg += bce; ++cntn; }
  }

  #pragma unroll
  for (int off = 32; off > 0; off >>= 1) {
    bpos += __shfl_down(bpos, off);
    bneg += __shfl_down(bneg, off);
    cntp += __shfl_down(cntp, off);
    cntn += __shfl_down(cntn, off);
  }
  if (lane == 0) {
    atomicAdd(&sbp, bpos);
    atomicAdd(&sbn, bneg);
    atomicAdd(&snp, (unsigned int)cntp);
    atomicAdd(&snn, (unsigned int)cntn);
  }
  __syncthreads();

  // ---- flush: sum the 4 wave rows, one global atomic per accumulator
  if (t < CNUM) {
    float v = lsS[0][t] + lsS[1][t] + lsS[2][t] + lsS[3][t];
    atomicAdd(&wsw->img[n].sS[t], (double)v);
  } else if (t >= 32 && t < 32 + CNUM) {
    int c = t - 32;
    float v = lsA[0][c] + lsA[1][c] + lsA[2][c] + lsA[3][c];
    atomicAdd(&wsw->img[n].sA[c], (double)v);
  } else if (t >= 64 && t < 64 + CNUM) {
    int c = t - 64;
    unsigned int v = lcS[0][c] + lcS[1][c] + lcS[2][c] + lcS[3][c];
    if (v) atomicAdd(&wsw->img[n].cS[c], v);
  } else if (t >= 96 && t < 96 + CNUM) {
    int c = t - 96;
    unsigned int v = lcA[0][c] + lcA[1][c] + lcA[2][c] + lcA[3][c];
    if (v) atomicAdd(&wsw->img[n].cA[c], v);
  } else if (t == 128) {
    atomicAdd(&wsw->bce_p, (double)sbp);
  } else if (t == 129) {
    atomicAdd(&wsw->bce_n, (double)sbn);
  } else if (t == 130) {
    atomicAdd(&wsw->np, snp);
  } else if (t == 131) {
    atomicAdd(&wsw->nn, snn);
  }
}

// ---------------------------------------------------------------- finalize
__global__ void k_final(const Ws* __restrict__ ws, float* __restrict__ out) {
  if (threadIdx.x == 0 && blockIdx.x == 0) {
    double segl = 0.0, attl = 0.0;
    for (int i = 0; i < NB; ++i) {
      const ImgAcc2* a = &ws->img[i];
      double totS = 0.0, totA = 0.0;
      for (int c = 0; c < CNUM; ++c) { totS += (double)a->cS[c]; totA += (double)a->cA[c]; }
      double numS = 0.0, denS = 0.0, numA = 0.0, denA = 0.0;
      for (int c = 0; c < CNUM; ++c) {
        double bS = (double)a->cS[c];
        double wS = (bS != 0.0 ? (1.0 - bS / totS) : 0.0) + 1.0;
        numS += wS * a->sS[c];
        denS += wS * bS;
        double bA = (double)a->cA[c];
        double wA = (bA != 0.0 ? (1.0 - bA / totA) : 0.0) + 1.0;
        numA += wA * a->sA[c];
        denA += wA * bA;
      }
      segl += numS / denS;
      attl += numA / denA;
    }
    double s = (double)ws->np + (double)ws->nn;
    double wpos = (double)ws->nn / s;
    double wneg = (double)ws->np / s;
    double edgel = (wpos * ws->bce_p + wneg * ws->bce_n) / (double)NPIX;
    out[0] = (float)(segl + 0.3 * edgel + 0.1 * attl);
  }
}

// ---------------------------------------------------------------- launch
extern "C" void kernel_launch(void* const* d_in, const int* in_sizes, int n_in,
                              void* d_out, int out_size, void* d_ws, size_t ws_size,
                              hipStream_t stream) {
  const float* segin   = (const float*)d_in[0];
  const float* edgein  = (const float*)d_in[1];
  const int*   segmask = (const int*)d_in[2];
  const int*   edgemask= (const int*)d_in[3];
  Ws* ws = (Ws*)d_ws;
  float* out = (float*)d_out;

  hipLaunchKernelGGL(k_init,  dim3(1),             dim3(256), 0, stream, ws);
  hipLaunchKernelGGL(k_fused, dim3(HW / TILE, NB), dim3(TPB), 0, stream, segin, edgein, segmask, edgemask, ws);
  hipLaunchKernelGGL(k_final, dim3(1),             dim3(1),   0, stream, ws, out);
}